// Round 1
// baseline (2310.786 us; speedup 1.0000x reference)
//
#include <hip/hip_runtime.h>

typedef _Float16 f16;
typedef _Float16 f16x8 __attribute__((ext_vector_type(8)));
typedef _Float16 f16x4 __attribute__((ext_vector_type(4)));
typedef float f32x4 __attribute__((ext_vector_type(4)));

#define MFMA_F16(A, B, C) __builtin_amdgcn_mfma_f32_16x16x32_f16(A, B, C, 0, 0, 0)

#define TM 128
#define TN 128
#define BK 64
// LDS: linear [128][64] f16 (LSTR=64, NO pad — global_load_lds requires the
// linear lane order; bank conflicts on ds_read_b128 are hidden behind MFMA in
// this 2-barrier structure [m97/m103: 912 TF with 1.7e7 conflicts; T2 null at 2ph])

// Async-stage a 128x64 f16 tile (row-major, leading dim ldg) into linear LDS.
// 256 threads x 4 chunks of 16B. LDS dest is wave-uniform base + lane*16B
// (chunk id c is lane-linear within each wave => layout contract satisfied).
__device__ __forceinline__ void stage_tile_async(const f16* __restrict__ g, int ldg,
                                                 f16* __restrict__ s) {
    const int t = threadIdx.x;
#pragma unroll
    for (int i = 0; i < 4; ++i) {
        int c = i * 256 + t;          // 0..1023 chunk id; 128 rows x 8 chunks of 8 f16
        int row = c >> 3, p = c & 7;
        __builtin_amdgcn_global_load_lds(
            (const __attribute__((address_space(1))) void*)(g + (size_t)row * ldg + p * 8),
            (__attribute__((address_space(3))) void*)(s + c * 8), 16, 0, 0);
    }
}

// ---------------- K1: H = silu(X @ W1^T) * (X @ W3^T), f16 out ----------------
__global__ __launch_bounds__(256) void k1_gate(
    const f16* __restrict__ A, int K,
    const f16* __restrict__ W1, const f16* __restrict__ W3,
    f16* __restrict__ Hout)
{
    __shared__ f16 As[TM * 64];
    __shared__ f16 B1s[TN * 64];
    __shared__ f16 B3s[TN * 64];

    // XCD-chunked bijective swizzle (nwg=2048, %8==0): each XCD gets a
    // contiguous 256-block chunk => shared A-rows/W-panels hit its private L2.
    const int nwg = gridDim.x;
    const int bid = blockIdx.x;
    const int swz = (bid & 7) * (nwg >> 3) + (bid >> 3);
    const int hb = swz & 15;   // hidden col-block (16)
    const int rb = swz >> 4;   // row-block (128)

    const int wave = threadIdx.x >> 6;
    const int lane = threadIdx.x & 63;
    const int wr = wave >> 1, wc = wave & 1;
    const int ln = lane & 15, lq = lane >> 4;

    f32x4 acc1[4][4] = {};
    f32x4 acc3[4][4] = {};

    const f16* Ab  = A  + (size_t)rb * TM * 2048;  // obs_f16 ld = 2048
    const f16* B1b = W1 + (size_t)hb * TN * K;
    const f16* B3b = W3 + (size_t)hb * TN * K;

    for (int k0 = 0; k0 < K; k0 += BK) {
        __syncthreads();
        stage_tile_async(Ab + k0, 2048, As);
        stage_tile_async(B1b + k0, K, B1s);
        stage_tile_async(B3b + k0, K, B3s);
        __syncthreads();  // compiler emits s_waitcnt vmcnt(0) => async loads landed
#pragma unroll
        for (int ks = 0; ks < 2; ++ks) {
            f16x8 af[4], b1f[4], b3f[4];
#pragma unroll
            for (int mi = 0; mi < 4; ++mi)
                af[mi] = *(const f16x8*)(As + (wr * 64 + mi * 16 + ln) * 64 + ks * 32 + lq * 8);
#pragma unroll
            for (int ni = 0; ni < 4; ++ni) {
                b1f[ni] = *(const f16x8*)(B1s + (wc * 64 + ni * 16 + ln) * 64 + ks * 32 + lq * 8);
                b3f[ni] = *(const f16x8*)(B3s + (wc * 64 + ni * 16 + ln) * 64 + ks * 32 + lq * 8);
            }
#pragma unroll
            for (int mi = 0; mi < 4; ++mi)
#pragma unroll
                for (int ni = 0; ni < 4; ++ni) {
                    acc1[mi][ni] = MFMA_F16(af[mi], b1f[ni], acc1[mi][ni]);
                    acc3[mi][ni] = MFMA_F16(af[mi], b3f[ni], acc3[mi][ni]);
                }
        }
    }

    // epilogue: C/D layout col = lane&15, row = (lane>>4)*4 + reg  [m89-verified]
    const int row0 = rb * TM + wr * 64;
    const int col0 = hb * TN + wc * 64;
#pragma unroll
    for (int mi = 0; mi < 4; ++mi)
#pragma unroll
        for (int r = 0; r < 4; ++r) {
            int row = row0 + mi * 16 + lq * 4 + r;
#pragma unroll
            for (int ni = 0; ni < 4; ++ni) {
                float g1 = acc1[mi][ni][r];
                float g3 = acc3[mi][ni][r];
                float h = g1 / (1.f + __expf(-g1)) * g3;  // silu(g1)*g3
                Hout[(size_t)row * 2048 + col0 + ni * 16 + ln] = (f16)h;
            }
        }
}

// ---------------- K2: raw = H @ W2^T (fp32 to d_out) + per-row partial ss ----------------
__global__ __launch_bounds__(256) void k2_out(
    const f16* __restrict__ Hm, const f16* __restrict__ W2,
    float* __restrict__ outp,   // d_out + g*1024, row stride 7168
    float* __restrict__ ssp)    // ss + g*8*16384, layout [cb][b]
{
    __shared__ f16 As[TM * 64];
    __shared__ f16 Bs[TN * 64];
    __shared__ float ssTile[TM];

    // XCD-chunked swizzle (nwg=1024): each XCD covers rb 0..15 x all cb =>
    // W2 panel (4 MB f16) resident in its L2, A-stripes shared.
    const int nwg = gridDim.x;
    const int bid = blockIdx.x;
    const int swz = (bid & 7) * (nwg >> 3) + (bid >> 3);
    const int cb = swz & 7;    // out col-block (8)
    const int rb = swz >> 3;   // row-block (128)

    const int wave = threadIdx.x >> 6;
    const int lane = threadIdx.x & 63;
    const int wr = wave >> 1, wc = wave & 1;
    const int ln = lane & 15, lq = lane >> 4;

    if (threadIdx.x < TM) ssTile[threadIdx.x] = 0.f;

    f32x4 acc[4][4] = {};

    const f16* Ab = Hm + (size_t)rb * TM * 2048;
    const f16* Bb = W2 + (size_t)cb * TN * 2048;

    for (int k0 = 0; k0 < 2048; k0 += BK) {
        __syncthreads();
        stage_tile_async(Ab + k0, 2048, As);
        stage_tile_async(Bb + k0, 2048, Bs);
        __syncthreads();
#pragma unroll
        for (int ks = 0; ks < 2; ++ks) {
            f16x8 af[4], bf[4];
#pragma unroll
            for (int mi = 0; mi < 4; ++mi)
                af[mi] = *(const f16x8*)(As + (wr * 64 + mi * 16 + ln) * 64 + ks * 32 + lq * 8);
#pragma unroll
            for (int ni = 0; ni < 4; ++ni)
                bf[ni] = *(const f16x8*)(Bs + (wc * 64 + ni * 16 + ln) * 64 + ks * 32 + lq * 8);
#pragma unroll
            for (int mi = 0; mi < 4; ++mi)
#pragma unroll
                for (int ni = 0; ni < 4; ++ni)
                    acc[mi][ni] = MFMA_F16(af[mi], bf[ni], acc[mi][ni]);
        }
    }

    const int lrow0 = wr * 64;
    const int gcol0 = cb * TN + wc * 64;
#pragma unroll
    for (int mi = 0; mi < 4; ++mi)
#pragma unroll
        for (int r = 0; r < 4; ++r) {
            int lrow = lrow0 + mi * 16 + lq * 4 + r;
            size_t grow = (size_t)(rb * TM + lrow);
            float s = 0.f;
#pragma unroll
            for (int ni = 0; ni < 4; ++ni) {
                float c = acc[mi][ni][r];
                s += c * c;
                outp[grow * 7168 + gcol0 + ni * 16 + ln] = c;
            }
            // 16 lanes (same lq) hold this row's 16 cols of each frag: butterfly over low 4 bits
            s += __shfl_xor(s, 1);
            s += __shfl_xor(s, 2);
            s += __shfl_xor(s, 4);
            s += __shfl_xor(s, 8);
            if (ln == 0) atomicAdd(&ssTile[lrow], s);  // ds_add_f32; waves 0/1 and 2/3 share rows
        }
    __syncthreads();
    if (threadIdx.x < TM)
        ssp[(size_t)cb * 16384 + rb * TM + threadIdx.x] = ssTile[threadIdx.x];
}

// ---------------- K3: in-place RMS norm + affine + term_embed ----------------
__global__ __launch_bounds__(256) void k3_norm(
    float* __restrict__ outp, const float* __restrict__ ss,
    const float* __restrict__ nw, const float* __restrict__ nb,
    const float* __restrict__ te)
{
    const int rrow = blockIdx.x;  // b*7 + g
    const int g = rrow % 7;
    const int b = rrow / 7;
    float ssum = 0.f;
#pragma unroll
    for (int cb = 0; cb < 8; ++cb) ssum += ss[(size_t)(g * 8 + cb) * 16384 + b];
    const float rinv = 1.0f / sqrtf(ssum * (1.0f / 1024.0f) + 1e-5f);
    const int t = threadIdx.x;
    float4* rowp = (float4*)(outp + (size_t)rrow * 1024);
    float4 x = rowp[t];
    float4 w = ((const float4*)nw)[t];
    float4 bb = ((const float4*)nb)[t];
    float4 e = ((const float4*)(te + g * 1024))[t];
    float4 o;
    o.x = x.x * rinv * w.x + bb.x + e.x;
    o.y = x.y * rinv * w.y + bb.y + e.y;
    o.z = x.z * rinv * w.z + bb.z + e.z;
    o.w = x.w * rinv * w.w + bb.w + e.w;
    rowp[t] = o;
}

// ---------------- K0: fp32 -> f16 convert (n multiple of 1024) ----------------
__global__ __launch_bounds__(256) void cvt_f16(const float* __restrict__ s, f16* __restrict__ d) {
    size_t i = (size_t)blockIdx.x * 256 + threadIdx.x;
    float4 v = ((const float4*)s)[i];
    f16x4 o = { (f16)v.x, (f16)v.y, (f16)v.z, (f16)v.w };
    ((f16x4*)d)[i] = o;
}

extern "C" void kernel_launch(void* const* d_in, const int* in_sizes, int n_in,
                              void* d_out, int out_size, void* d_ws, size_t ws_size,
                              hipStream_t stream) {
    const float* obs  = (const float*)d_in[0];
    const float* w1g0 = (const float*)d_in[1];
    const float* w3g0 = (const float*)d_in[2];
    const float* w2g0 = (const float*)d_in[3];
    const float* w1r  = (const float*)d_in[4];
    const float* w3r  = (const float*)d_in[5];
    const float* w2r  = (const float*)d_in[6];
    const float* nw   = (const float*)d_in[7];
    const float* nb   = (const float*)d_in[8];
    const float* te   = (const float*)d_in[9];

    // ws layout (f16 elems): obs 33554432 | w1g0 1048576 | w3g0 1048576 | w2g0 2097152
    //                        | w1r 3145728 | w3r 3145728 | w2r 12582912 | Hbuf 33554432 | ss (f32)
    // total ~184 MB
    f16* obs_h  = (f16*)d_ws;
    f16* w1g0_h = obs_h  + 33554432;
    f16* w3g0_h = w1g0_h + 1048576;
    f16* w2g0_h = w3g0_h + 1048576;
    f16* w1r_h  = w2g0_h + 2097152;
    f16* w3r_h  = w1r_h  + 3145728;
    f16* w2r_h  = w3r_h  + 3145728;
    f16* Hbuf   = w2r_h  + 12582912;
    float* ssb  = (float*)(Hbuf + 33554432);

    cvt_f16<<<33554432 / 1024, 256, 0, stream>>>(obs, obs_h);
    cvt_f16<<<1048576 / 1024, 256, 0, stream>>>(w1g0, w1g0_h);
    cvt_f16<<<1048576 / 1024, 256, 0, stream>>>(w3g0, w3g0_h);
    cvt_f16<<<2097152 / 1024, 256, 0, stream>>>(w2g0, w2g0_h);
    cvt_f16<<<3145728 / 1024, 256, 0, stream>>>(w1r, w1r_h);
    cvt_f16<<<3145728 / 1024, 256, 0, stream>>>(w3r, w3r_h);
    cvt_f16<<<12582912 / 1024, 256, 0, stream>>>(w2r, w2r_h);

    for (int g = 0; g < 7; ++g) {
        const f16* A  = obs_h + (g == 0 ? 0 : 512 + (g - 1) * 256);
        int K         = (g == 0) ? 512 : 256;
        const f16* W1 = (g == 0) ? w1g0_h : w1r_h + (size_t)(g - 1) * 2048 * 256;
        const f16* W3 = (g == 0) ? w3g0_h : w3r_h + (size_t)(g - 1) * 2048 * 256;
        const f16* W2 = (g == 0) ? w2g0_h : w2r_h + (size_t)(g - 1) * 1024 * 2048;
        k1_gate<<<dim3(16 * 128), 256, 0, stream>>>(A, K, W1, W3, Hbuf);
        k2_out<<<dim3(8 * 128), 256, 0, stream>>>(Hbuf, W2, (float*)d_out + g * 1024,
                                                  ssb + (size_t)g * 8 * 16384);
    }
    k3_norm<<<114688, 256, 0, stream>>>((float*)d_out, ssb, nw, nb, te);
}

// Round 2
// 2199.726 us; speedup vs baseline: 1.0505x; 1.0505x over previous
//
#include <hip/hip_runtime.h>

typedef _Float16 f16;
typedef _Float16 f16x8 __attribute__((ext_vector_type(8)));
typedef _Float16 f16x4 __attribute__((ext_vector_type(4)));
typedef float f32x4 __attribute__((ext_vector_type(4)));

#define MFMA_F16(A, B, C) __builtin_amdgcn_mfma_f32_16x16x32_f16(A, B, C, 0, 0, 0)

#define TM 128
#define TN 128
#define BK 64
#define LSTR 80  // LDS row stride in f16 elems: 64 + 16 pad = 160 B (4-way max on frag ds_read)

// Stage a 128x64 f16 tile (row-major, leading dim ldg) into LDS. 256 threads,
// 4 x 16B chunks each. Coalesced 128 B per global row segment. (Reg-staged:
// compiler hoists next-tile global loads above the barrier => overlap. This
// measured BETTER than global_load_lds+linear LDS on this workload: 2199 vs 2311.)
__device__ __forceinline__ void stage_tile(const f16* __restrict__ g, int ldg,
                                           f16* __restrict__ s) {
    const int t = threadIdx.x;
#pragma unroll
    for (int i = 0; i < 4; ++i) {
        int c = i * 256 + t;          // 0..1023 chunk id
        int row = c >> 3, p = c & 7;  // 128 rows x 8 chunks of 8 f16
        uint4 v = *(const uint4*)(g + (size_t)row * ldg + p * 8);
        *(uint4*)(s + row * LSTR + p * 8) = v;
    }
}

// ---------------- K1: H = silu(X @ W1^T) * (X @ W3^T), f16 out ----------------
__global__ __launch_bounds__(256) void k1_gate(
    const f16* __restrict__ A, int K,
    const f16* __restrict__ W1, const f16* __restrict__ W3,
    f16* __restrict__ Hout)
{
    __shared__ f16 smem[3 * TM * LSTR];  // As | B1s | B3s; reused as epilogue bounce tile
    f16* As  = smem;
    f16* B1s = smem + TM * LSTR;
    f16* B3s = smem + 2 * TM * LSTR;

    const int hb = blockIdx.x;  // hidden col-block (16)
    const int rb = blockIdx.y;  // row-block (128)
    const int wave = threadIdx.x >> 6;
    const int lane = threadIdx.x & 63;
    const int wr = wave >> 1, wc = wave & 1;
    const int ln = lane & 15, lq = lane >> 4;

    f32x4 acc1[4][4] = {};
    f32x4 acc3[4][4] = {};

    const f16* Ab  = A  + (size_t)rb * TM * 2048;  // obs_f16 ld = 2048
    const f16* B1b = W1 + (size_t)hb * TN * K;
    const f16* B3b = W3 + (size_t)hb * TN * K;

    for (int k0 = 0; k0 < K; k0 += BK) {
        __syncthreads();
        stage_tile(Ab + k0, 2048, As);
        stage_tile(B1b + k0, K, B1s);
        stage_tile(B3b + k0, K, B3s);
        __syncthreads();
#pragma unroll
        for (int ks = 0; ks < 2; ++ks) {
            f16x8 af[4], b1f[4], b3f[4];
#pragma unroll
            for (int mi = 0; mi < 4; ++mi)
                af[mi] = *(const f16x8*)(As + (wr * 64 + mi * 16 + ln) * LSTR + ks * 32 + lq * 8);
#pragma unroll
            for (int ni = 0; ni < 4; ++ni) {
                b1f[ni] = *(const f16x8*)(B1s + (wc * 64 + ni * 16 + ln) * LSTR + ks * 32 + lq * 8);
                b3f[ni] = *(const f16x8*)(B3s + (wc * 64 + ni * 16 + ln) * LSTR + ks * 32 + lq * 8);
            }
#pragma unroll
            for (int mi = 0; mi < 4; ++mi)
#pragma unroll
                for (int ni = 0; ni < 4; ++ni) {
                    acc1[mi][ni] = MFMA_F16(af[mi], b1f[ni], acc1[mi][ni]);
                    acc3[mi][ni] = MFMA_F16(af[mi], b3f[ni], acc3[mi][ni]);
                }
        }
    }

    // ---- epilogue: silu(g1)*g3 -> LDS bounce tile -> coalesced f16x8 stores ----
    // C/D layout col = lane&15, row = (lane>>4)*4 + reg  [m89-verified]
    __syncthreads();                 // all waves done reading As/B1s/B3s
    const int CT = 136;              // 128 + 8 pad: row stride 272 B => +4 bank skew/row
    f16* Ct = smem;                  // [128][136] f16 = 34,816 B (fits in 61,440 B)
#pragma unroll
    for (int mi = 0; mi < 4; ++mi)
#pragma unroll
        for (int r = 0; r < 4; ++r) {
            int lrow = wr * 64 + mi * 16 + lq * 4 + r;
#pragma unroll
            for (int ni = 0; ni < 4; ++ni) {
                float g1 = acc1[mi][ni][r];
                float g3 = acc3[mi][ni][r];
                float h = g1 / (1.f + __expf(-g1)) * g3;  // silu(g1)*g3
                Ct[lrow * CT + wc * 64 + ni * 16 + ln] = (f16)h;
            }
        }
    __syncthreads();
    // copy 128 rows x 128 f16 (2048 x 16B chunks, 8/thread), fully coalesced
    const size_t row0g = (size_t)rb * TM;
    const int col0g = hb * TN;
    const int t = threadIdx.x;
#pragma unroll
    for (int i = 0; i < 8; ++i) {
        int c = i * 256 + t;
        int row = c >> 4, p = c & 15;   // 128 rows x 16 chunks of 8 f16
        *(uint4*)(Hout + (row0g + row) * 2048 + col0g + p * 8) =
            *(const uint4*)(Ct + row * CT + p * 8);
    }
}

// ---------------- K2: raw = H @ W2^T (fp32 to d_out) + per-row partial ss ----------------
__global__ __launch_bounds__(256) void k2_out(
    const f16* __restrict__ Hm, const f16* __restrict__ W2,
    float* __restrict__ outp,   // d_out + g*1024, row stride 7168
    float* __restrict__ ssp)    // ss + g*8*16384, layout [cb][b]
{
    __shared__ f16 smem[2 * TM * LSTR];  // As | Bs; reused as fp32 epilogue bounce
    __shared__ float ssTile[TM];
    f16* As = smem;
    f16* Bs = smem + TM * LSTR;

    const int cb = blockIdx.x;  // out col-block (8)
    const int rb = blockIdx.y;  // row-block (128)
    const int wave = threadIdx.x >> 6;
    const int lane = threadIdx.x & 63;
    const int wr = wave >> 1, wc = wave & 1;
    const int ln = lane & 15, lq = lane >> 4;

    if (threadIdx.x < TM) ssTile[threadIdx.x] = 0.f;

    f32x4 acc[4][4] = {};

    const f16* Ab = Hm + (size_t)rb * TM * 2048;
    const f16* Bb = W2 + (size_t)cb * TN * 2048;

    for (int k0 = 0; k0 < 2048; k0 += BK) {
        __syncthreads();
        stage_tile(Ab + k0, 2048, As);
        stage_tile(Bb + k0, 2048, Bs);
        __syncthreads();
#pragma unroll
        for (int ks = 0; ks < 2; ++ks) {
            f16x8 af[4], bf[4];
#pragma unroll
            for (int mi = 0; mi < 4; ++mi)
                af[mi] = *(const f16x8*)(As + (wr * 64 + mi * 16 + ln) * LSTR + ks * 32 + lq * 8);
#pragma unroll
            for (int ni = 0; ni < 4; ++ni)
                bf[ni] = *(const f16x8*)(Bs + (wc * 64 + ni * 16 + ln) * LSTR + ks * 32 + lq * 8);
#pragma unroll
            for (int mi = 0; mi < 4; ++mi)
#pragma unroll
                for (int ni = 0; ni < 4; ++ni)
                    acc[mi][ni] = MFMA_F16(af[mi], bf[ni], acc[mi][ni]);
        }
    }

    // ---- ss partial sums (unchanged arithmetic) ----
#pragma unroll
    for (int mi = 0; mi < 4; ++mi)
#pragma unroll
        for (int r = 0; r < 4; ++r) {
            int lrow = wr * 64 + mi * 16 + lq * 4 + r;
            float s = 0.f;
#pragma unroll
            for (int ni = 0; ni < 4; ++ni) {
                float c = acc[mi][ni][r];
                s += c * c;
            }
            s += __shfl_xor(s, 1);
            s += __shfl_xor(s, 2);
            s += __shfl_xor(s, 4);
            s += __shfl_xor(s, 8);
            if (ln == 0) atomicAdd(&ssTile[lrow], s);
        }

    // ---- fp32 output via LDS bounce: 2 passes of 64 rows (33,792 B tile) ----
    const int CTF = 132;  // 128 + 4 pad: row stride 528 B => +4 bank skew/row
    float* Ct = (float*)smem;
    const int t = threadIdx.x;
#pragma unroll
    for (int pass = 0; pass < 2; ++pass) {
        __syncthreads();  // pass0: waves done reading As/Bs; pass1: copy of pass0 done
        if (wr == pass) {
#pragma unroll
            for (int mi = 0; mi < 4; ++mi)
#pragma unroll
                for (int r = 0; r < 4; ++r) {
                    int lrow = mi * 16 + lq * 4 + r;  // 0..63 within this pass
#pragma unroll
                    for (int ni = 0; ni < 4; ++ni)
                        Ct[lrow * CTF + wc * 64 + ni * 16 + ln] = acc[mi][ni][r];
                }
        }
        __syncthreads();
        // copy 64 rows x 128 f32 (2048 x 16B chunks, 8/thread), coalesced
#pragma unroll
        for (int i = 0; i < 8; ++i) {
            int c = i * 256 + t;
            int row = c >> 5, p = c & 31;  // 64 rows x 32 chunks of 4 f32
            size_t grow = (size_t)rb * TM + pass * 64 + row;
            *(float4*)(outp + grow * 7168 + cb * TN + p * 4) =
                *(const float4*)(Ct + row * CTF + p * 4);
        }
    }
    __syncthreads();
    if (threadIdx.x < TM)
        ssp[(size_t)cb * 16384 + rb * TM + threadIdx.x] = ssTile[threadIdx.x];
}

// ---------------- K3: in-place RMS norm + affine + term_embed ----------------
__global__ __launch_bounds__(256) void k3_norm(
    float* __restrict__ outp, const float* __restrict__ ss,
    const float* __restrict__ nw, const float* __restrict__ nb,
    const float* __restrict__ te)
{
    const int rrow = blockIdx.x;  // b*7 + g
    const int g = rrow % 7;
    const int b = rrow / 7;
    float ssum = 0.f;
#pragma unroll
    for (int cb = 0; cb < 8; ++cb) ssum += ss[(size_t)(g * 8 + cb) * 16384 + b];
    const float rinv = 1.0f / sqrtf(ssum * (1.0f / 1024.0f) + 1e-5f);
    const int t = threadIdx.x;
    float4* rowp = (float4*)(outp + (size_t)rrow * 1024);
    float4 x = rowp[t];
    float4 w = ((const float4*)nw)[t];
    float4 bb = ((const float4*)nb)[t];
    float4 e = ((const float4*)(te + g * 1024))[t];
    float4 o;
    o.x = x.x * rinv * w.x + bb.x + e.x;
    o.y = x.y * rinv * w.y + bb.y + e.y;
    o.z = x.z * rinv * w.z + bb.z + e.z;
    o.w = x.w * rinv * w.w + bb.w + e.w;
    rowp[t] = o;
}

// ---------------- K0: fp32 -> f16 convert (n multiple of 1024) ----------------
__global__ __launch_bounds__(256) void cvt_f16(const float* __restrict__ s, f16* __restrict__ d) {
    size_t i = (size_t)blockIdx.x * 256 + threadIdx.x;
    float4 v = ((const float4*)s)[i];
    f16x4 o = { (f16)v.x, (f16)v.y, (f16)v.z, (f16)v.w };
    ((f16x4*)d)[i] = o;
}

extern "C" void kernel_launch(void* const* d_in, const int* in_sizes, int n_in,
                              void* d_out, int out_size, void* d_ws, size_t ws_size,
                              hipStream_t stream) {
    const float* obs  = (const float*)d_in[0];
    const float* w1g0 = (const float*)d_in[1];
    const float* w3g0 = (const float*)d_in[2];
    const float* w2g0 = (const float*)d_in[3];
    const float* w1r  = (const float*)d_in[4];
    const float* w3r  = (const float*)d_in[5];
    const float* w2r  = (const float*)d_in[6];
    const float* nw   = (const float*)d_in[7];
    const float* nb   = (const float*)d_in[8];
    const float* te   = (const float*)d_in[9];

    // ws layout (f16 elems): obs 33554432 | w1g0 1048576 | w3g0 1048576 | w2g0 2097152
    //                        | w1r 3145728 | w3r 3145728 | w2r 12582912 | Hbuf 33554432 | ss (f32)
    // total ~184 MB
    f16* obs_h  = (f16*)d_ws;
    f16* w1g0_h = obs_h  + 33554432;
    f16* w3g0_h = w1g0_h + 1048576;
    f16* w2g0_h = w3g0_h + 1048576;
    f16* w1r_h  = w2g0_h + 2097152;
    f16* w3r_h  = w1r_h  + 3145728;
    f16* w2r_h  = w3r_h  + 3145728;
    f16* Hbuf   = w2r_h  + 12582912;
    float* ssb  = (float*)(Hbuf + 33554432);

    cvt_f16<<<33554432 / 1024, 256, 0, stream>>>(obs, obs_h);
    cvt_f16<<<1048576 / 1024, 256, 0, stream>>>(w1g0, w1g0_h);
    cvt_f16<<<1048576 / 1024, 256, 0, stream>>>(w3g0, w3g0_h);
    cvt_f16<<<2097152 / 1024, 256, 0, stream>>>(w2g0, w2g0_h);
    cvt_f16<<<3145728 / 1024, 256, 0, stream>>>(w1r, w1r_h);
    cvt_f16<<<3145728 / 1024, 256, 0, stream>>>(w3r, w3r_h);
    cvt_f16<<<12582912 / 1024, 256, 0, stream>>>(w2r, w2r_h);

    for (int g = 0; g < 7; ++g) {
        const f16* A  = obs_h + (g == 0 ? 0 : 512 + (g - 1) * 256);
        int K         = (g == 0) ? 512 : 256;
        const f16* W1 = (g == 0) ? w1g0_h : w1r_h + (size_t)(g - 1) * 2048 * 256;
        const f16* W3 = (g == 0) ? w3g0_h : w3r_h + (size_t)(g - 1) * 2048 * 256;
        const f16* W2 = (g == 0) ? w2g0_h : w2r_h + (size_t)(g - 1) * 1024 * 2048;
        k1_gate<<<dim3(16, 128), 256, 0, stream>>>(A, K, W1, W3, Hbuf);
        k2_out<<<dim3(8, 128), 256, 0, stream>>>(Hbuf, W2, (float*)d_out + g * 1024,
                                                 ssb + (size_t)g * 8 * 16384);
    }
    k3_norm<<<114688, 256, 0, stream>>>((float*)d_out, ssb, nw, nb, te);
}

// Round 3
// 1941.222 us; speedup vs baseline: 1.1904x; 1.1332x over previous
//
#include <hip/hip_runtime.h>

typedef _Float16 f16;
typedef _Float16 f16x8 __attribute__((ext_vector_type(8)));
typedef _Float16 f16x4 __attribute__((ext_vector_type(4)));
typedef float f32x4 __attribute__((ext_vector_type(4)));

#define MFMA_F16(A, B, C) __builtin_amdgcn_mfma_f32_16x16x32_f16(A, B, C, 0, 0, 0)

#define TM 128
#define TN 128
#define BK 64
#define LSTR 80  // k1 LDS row stride in f16 elems: 64 + 16 pad

// Reg-staged tile for k1 (measured-best there: 2199 baseline component).
__device__ __forceinline__ void stage_tile(const f16* __restrict__ g, int ldg,
                                           f16* __restrict__ s) {
    const int t = threadIdx.x;
#pragma unroll
    for (int i = 0; i < 4; ++i) {
        int c = i * 256 + t;          // 0..1023 chunk id
        int row = c >> 3, p = c & 7;  // 128 rows x 8 chunks of 8 f16
        uint4 v = *(const uint4*)(g + (size_t)row * ldg + p * 8);
        *(uint4*)(s + row * LSTR + p * 8) = v;
    }
}

// ---------------- K1: H = silu(X @ W1^T) * (X @ W3^T), f16 out (unchanged) ----------------
__global__ __launch_bounds__(256) void k1_gate(
    const f16* __restrict__ A, int K,
    const f16* __restrict__ W1, const f16* __restrict__ W3,
    f16* __restrict__ Hout)
{
    __shared__ f16 smem[3 * TM * LSTR];
    f16* As  = smem;
    f16* B1s = smem + TM * LSTR;
    f16* B3s = smem + 2 * TM * LSTR;

    const int hb = blockIdx.x;
    const int rb = blockIdx.y;
    const int wave = threadIdx.x >> 6;
    const int lane = threadIdx.x & 63;
    const int wr = wave >> 1, wc = wave & 1;
    const int ln = lane & 15, lq = lane >> 4;

    f32x4 acc1[4][4] = {};
    f32x4 acc3[4][4] = {};

    const f16* Ab  = A  + (size_t)rb * TM * 2048;
    const f16* B1b = W1 + (size_t)hb * TN * K;
    const f16* B3b = W3 + (size_t)hb * TN * K;

    for (int k0 = 0; k0 < K; k0 += BK) {
        __syncthreads();
        stage_tile(Ab + k0, 2048, As);
        stage_tile(B1b + k0, K, B1s);
        stage_tile(B3b + k0, K, B3s);
        __syncthreads();
#pragma unroll
        for (int ks = 0; ks < 2; ++ks) {
            f16x8 af[4], b1f[4], b3f[4];
#pragma unroll
            for (int mi = 0; mi < 4; ++mi)
                af[mi] = *(const f16x8*)(As + (wr * 64 + mi * 16 + ln) * LSTR + ks * 32 + lq * 8);
#pragma unroll
            for (int ni = 0; ni < 4; ++ni) {
                b1f[ni] = *(const f16x8*)(B1s + (wc * 64 + ni * 16 + ln) * LSTR + ks * 32 + lq * 8);
                b3f[ni] = *(const f16x8*)(B3s + (wc * 64 + ni * 16 + ln) * LSTR + ks * 32 + lq * 8);
            }
#pragma unroll
            for (int mi = 0; mi < 4; ++mi)
#pragma unroll
                for (int ni = 0; ni < 4; ++ni) {
                    acc1[mi][ni] = MFMA_F16(af[mi], b1f[ni], acc1[mi][ni]);
                    acc3[mi][ni] = MFMA_F16(af[mi], b3f[ni], acc3[mi][ni]);
                }
        }
    }

    __syncthreads();
    const int CT = 136;
    f16* Ct = smem;
#pragma unroll
    for (int mi = 0; mi < 4; ++mi)
#pragma unroll
        for (int r = 0; r < 4; ++r) {
            int lrow = wr * 64 + mi * 16 + lq * 4 + r;
#pragma unroll
            for (int ni = 0; ni < 4; ++ni) {
                float g1 = acc1[mi][ni][r];
                float g3 = acc3[mi][ni][r];
                float h = g1 / (1.f + __expf(-g1)) * g3;
                Ct[lrow * CT + wc * 64 + ni * 16 + ln] = (f16)h;
            }
        }
    __syncthreads();
    const size_t row0g = (size_t)rb * TM;
    const int col0g = hb * TN;
    const int t = threadIdx.x;
#pragma unroll
    for (int i = 0; i < 8; ++i) {
        int c = i * 256 + t;
        int row = c >> 4, p = c & 15;
        *(uint4*)(Hout + (row0g + row) * 2048 + col0g + p * 8) =
            *(const uint4*)(Ct + row * CT + p * 8);
    }
}

// ---------------- K2: 256^2 tile, BK=64, counted-vmcnt pipeline (T2+T4+T5) ----------------
// M=16384, N=1024, K=2048. Grid 256 blocks (1/CU), 512 threads (8 waves, 2Mx4N).
// LDS: A/B double-buffered 256x64 f16 tiles, linear layout, row-XOR swizzle
// (p ^= row&7) applied on the GLOBAL SOURCE of global_load_lds and on ds_read
// addresses (both-sides-or-neither, rule #21). vmcnt(8) counted wait (T4):
// next tile's 8 loads stay in flight across barriers.
#define K2NT 32
__global__ __launch_bounds__(512, 2) void k2_out(
    const f16* __restrict__ Hm, const f16* __restrict__ W2,
    float* __restrict__ outp,   // d_out + g*1024, row stride 7168
    float* __restrict__ ssp)    // ss + g*4*16384, layout [cb][b]
{
    __shared__ f16 As[2][256 * 64];   // 32 KB each buf
    __shared__ f16 Bs[2][256 * 64];
    __shared__ float ssTile[256];

    // XCD-chunked swizzle: nwg=256, 32 per XCD => each XCD runs 8 rb x 4 cb:
    // A-stripes shared in its L2; W2 (4 MB f16) L2-resident.
    const int bid = blockIdx.x;
    const int swz = (bid & 7) * 32 + (bid >> 3);
    const int cb = swz & 3;   // out col-block (4)
    const int rb = swz >> 2;  // row-block (64)

    const int wid = threadIdx.x >> 6;
    const int lane = threadIdx.x & 63;
    const int wm = wid >> 2;  // 0..1 (M half)
    const int wn = wid & 3;   // 0..3 (N quarter)
    const int ln = lane & 15, lq = lane >> 4;

    if (threadIdx.x < 256) ssTile[threadIdx.x] = 0.f;

    const f16* Ab = Hm + (size_t)rb * 256 * 2048;
    const f16* Bb = W2 + (size_t)cb * 256 * 2048;

    // Stage K-tile kt (A and B, 32 KB each) into buf b. 8 global_load_lds per
    // thread => vmcnt +8 per wave per tile. LDS dest linear (lane-order);
    // global source pre-swizzled: chunk (row,p) sources logical (row, p^(row&7)).
#define K2_STAGE(kt, b)                                                                     \
    {                                                                                       \
        const f16* ga = Ab + (kt) * 64;                                                     \
        const f16* gb = Bb + (kt) * 64;                                                     \
        const int tt = threadIdx.x;                                                         \
        _Pragma("unroll")                                                                   \
        for (int i = 0; i < 4; ++i) {                                                       \
            int c = i * 512 + tt;                                                           \
            int row = c >> 3, p = c & 7, ps = p ^ (row & 7);                                \
            __builtin_amdgcn_global_load_lds(                                               \
                (const __attribute__((address_space(1))) void*)(ga + (size_t)row * 2048 + ps * 8), \
                (__attribute__((address_space(3))) void*)(&As[b][c * 8]), 16, 0, 0);        \
        }                                                                                   \
        _Pragma("unroll")                                                                   \
        for (int i = 0; i < 4; ++i) {                                                       \
            int c = i * 512 + tt;                                                           \
            int row = c >> 3, p = c & 7, ps = p ^ (row & 7);                                \
            __builtin_amdgcn_global_load_lds(                                               \
                (const __attribute__((address_space(1))) void*)(gb + (size_t)row * 2048 + ps * 8), \
                (__attribute__((address_space(3))) void*)(&Bs[b][c * 8]), 16, 0, 0);        \
        }                                                                                   \
    }

    K2_STAGE(0, 0);
    K2_STAGE(1, 1);

    f32x4 acc[8][4] = {};

    for (int t = 0; t < K2NT; ++t) {
        const int b = t & 1;
        // tile t landed (own wave's 8 oldest loads); t+1 may stay in flight (T4)
        asm volatile("s_waitcnt vmcnt(8)" ::: "memory");
        __builtin_amdgcn_sched_barrier(0);
        __builtin_amdgcn_s_barrier();   // all waves' chunks of tile t in LDS

        const char* Ap = (const char*)&As[b][0];
        const char* Bp = (const char*)&Bs[b][0];

        f16x8 bf[4][2], af[4][2];
#pragma unroll
        for (int ni = 0; ni < 4; ++ni)
#pragma unroll
            for (int ks = 0; ks < 2; ++ks) {
                int row = wn * 64 + ni * 16 + ln;
                bf[ni][ks] = *(const f16x8*)(Bp + row * 128 + ((ks * 64 + lq * 16) ^ ((row & 7) << 4)));
            }
#pragma unroll
        for (int mi = 0; mi < 4; ++mi)
#pragma unroll
            for (int ks = 0; ks < 2; ++ks) {
                int row = wm * 128 + mi * 16 + ln;
                af[mi][ks] = *(const f16x8*)(Ap + row * 128 + ((ks * 64 + lq * 16) ^ ((row & 7) << 4)));
            }
        asm volatile("s_waitcnt lgkmcnt(0)" ::: "memory");
        __builtin_amdgcn_sched_barrier(0);

        __builtin_amdgcn_s_setprio(1);
#pragma unroll
        for (int mi = 0; mi < 4; ++mi)
#pragma unroll
            for (int ni = 0; ni < 4; ++ni) {
                acc[mi][ni] = MFMA_F16(af[mi][0], bf[ni][0], acc[mi][ni]);
                acc[mi][ni] = MFMA_F16(af[mi][1], bf[ni][1], acc[mi][ni]);
            }
        __builtin_amdgcn_s_setprio(0);

        // reload af with M-half 1 (reuses regs; WAR handled by compiler)
#pragma unroll
        for (int mi = 0; mi < 4; ++mi)
#pragma unroll
            for (int ks = 0; ks < 2; ++ks) {
                int row = wm * 128 + 64 + mi * 16 + ln;
                af[mi][ks] = *(const f16x8*)(Ap + row * 128 + ((ks * 64 + lq * 16) ^ ((row & 7) << 4)));
            }
        asm volatile("s_waitcnt lgkmcnt(0)" ::: "memory");  // ALL reads of buf b done
        __builtin_amdgcn_sched_barrier(0);
        __builtin_amdgcn_s_barrier();   // every wave done reading => overwrite safe

        K2_STAGE((t + 2) & (K2NT - 1), b);  // wraps at end: 2 redundant tiles, keeps vmcnt uniform

        __builtin_amdgcn_s_setprio(1);
#pragma unroll
        for (int mi = 0; mi < 4; ++mi)
#pragma unroll
            for (int ni = 0; ni < 4; ++ni) {
                acc[4 + mi][ni] = MFMA_F16(af[mi][0], bf[ni][0], acc[4 + mi][ni]);
                acc[4 + mi][ni] = MFMA_F16(af[mi][1], bf[ni][1], acc[4 + mi][ni]);
            }
        __builtin_amdgcn_s_setprio(0);
    }

    // ---- epilogue: ss partials + direct fp32 stores ----
    const size_t grow0 = (size_t)rb * 256 + wm * 128;
    const int gcol0 = cb * 256 + wn * 64;
#pragma unroll
    for (int mi8 = 0; mi8 < 8; ++mi8)
#pragma unroll
        for (int r = 0; r < 4; ++r) {
            int lrl = (mi8 >> 2) * 64 + (mi8 & 3) * 16 + lq * 4 + r;  // within wm half
            int lrow = wm * 128 + lrl;
            size_t grow = grow0 + lrl;
            float s = 0.f;
#pragma unroll
            for (int ni = 0; ni < 4; ++ni) {
                float c = acc[mi8][ni][r];
                s += c * c;
                outp[grow * 7168 + gcol0 + ni * 16 + ln] = c;
            }
            s += __shfl_xor(s, 1);
            s += __shfl_xor(s, 2);
            s += __shfl_xor(s, 4);
            s += __shfl_xor(s, 8);
            if (ln == 0) atomicAdd(&ssTile[lrow], s);
        }
    __syncthreads();  // full drain OK here (pipeline finished; dummy loads land harmlessly)
    if (threadIdx.x < 256)
        ssp[(size_t)cb * 16384 + rb * 256 + threadIdx.x] = ssTile[threadIdx.x];
}

// ---------------- K3: in-place RMS norm + affine + term_embed ----------------
__global__ __launch_bounds__(256) void k3_norm(
    float* __restrict__ outp, const float* __restrict__ ss,
    const float* __restrict__ nw, const float* __restrict__ nb,
    const float* __restrict__ te)
{
    const int rrow = blockIdx.x;  // b*7 + g
    const int g = rrow % 7;
    const int b = rrow / 7;
    float ssum = 0.f;
#pragma unroll
    for (int cb = 0; cb < 4; ++cb) ssum += ss[(size_t)(g * 4 + cb) * 16384 + b];
    const float rinv = 1.0f / sqrtf(ssum * (1.0f / 1024.0f) + 1e-5f);
    const int t = threadIdx.x;
    float4* rowp = (float4*)(outp + (size_t)rrow * 1024);
    float4 x = rowp[t];
    float4 w = ((const float4*)nw)[t];
    float4 bb = ((const float4*)nb)[t];
    float4 e = ((const float4*)(te + g * 1024))[t];
    float4 o;
    o.x = x.x * rinv * w.x + bb.x + e.x;
    o.y = x.y * rinv * w.y + bb.y + e.y;
    o.z = x.z * rinv * w.z + bb.z + e.z;
    o.w = x.w * rinv * w.w + bb.w + e.w;
    rowp[t] = o;
}

// ---------------- K0: fp32 -> f16 convert (n multiple of 1024) ----------------
__global__ __launch_bounds__(256) void cvt_f16(const float* __restrict__ s, f16* __restrict__ d) {
    size_t i = (size_t)blockIdx.x * 256 + threadIdx.x;
    float4 v = ((const float4*)s)[i];
    f16x4 o = { (f16)v.x, (f16)v.y, (f16)v.z, (f16)v.w };
    ((f16x4*)d)[i] = o;
}

extern "C" void kernel_launch(void* const* d_in, const int* in_sizes, int n_in,
                              void* d_out, int out_size, void* d_ws, size_t ws_size,
                              hipStream_t stream) {
    const float* obs  = (const float*)d_in[0];
    const float* w1g0 = (const float*)d_in[1];
    const float* w3g0 = (const float*)d_in[2];
    const float* w2g0 = (const float*)d_in[3];
    const float* w1r  = (const float*)d_in[4];
    const float* w3r  = (const float*)d_in[5];
    const float* w2r  = (const float*)d_in[6];
    const float* nw   = (const float*)d_in[7];
    const float* nb   = (const float*)d_in[8];
    const float* te   = (const float*)d_in[9];

    f16* obs_h  = (f16*)d_ws;
    f16* w1g0_h = obs_h  + 33554432;
    f16* w3g0_h = w1g0_h + 1048576;
    f16* w2g0_h = w3g0_h + 1048576;
    f16* w1r_h  = w2g0_h + 2097152;
    f16* w3r_h  = w1r_h  + 3145728;
    f16* w2r_h  = w3r_h  + 3145728;
    f16* Hbuf   = w2r_h  + 12582912;
    float* ssb  = (float*)(Hbuf + 33554432);

    cvt_f16<<<33554432 / 1024, 256, 0, stream>>>(obs, obs_h);
    cvt_f16<<<1048576 / 1024, 256, 0, stream>>>(w1g0, w1g0_h);
    cvt_f16<<<1048576 / 1024, 256, 0, stream>>>(w3g0, w3g0_h);
    cvt_f16<<<2097152 / 1024, 256, 0, stream>>>(w2g0, w2g0_h);
    cvt_f16<<<3145728 / 1024, 256, 0, stream>>>(w1r, w1r_h);
    cvt_f16<<<3145728 / 1024, 256, 0, stream>>>(w3r, w3r_h);
    cvt_f16<<<12582912 / 1024, 256, 0, stream>>>(w2r, w2r_h);

    for (int g = 0; g < 7; ++g) {
        const f16* A  = obs_h + (g == 0 ? 0 : 512 + (g - 1) * 256);
        int K         = (g == 0) ? 512 : 256;
        const f16* W1 = (g == 0) ? w1g0_h : w1r_h + (size_t)(g - 1) * 2048 * 256;
        const f16* W3 = (g == 0) ? w3g0_h : w3r_h + (size_t)(g - 1) * 2048 * 256;
        const f16* W2 = (g == 0) ? w2g0_h : w2r_h + (size_t)(g - 1) * 1024 * 2048;
        k1_gate<<<dim3(16, 128), 256, 0, stream>>>(A, K, W1, W3, Hbuf);
        k2_out<<<256, 512, 0, stream>>>(Hbuf, W2, (float*)d_out + g * 1024,
                                        ssb + (size_t)g * 4 * 16384);
    }
    k3_norm<<<114688, 256, 0, stream>>>((float*)d_out, ssb, nw, nb, te);
}

// Round 4
// 1703.058 us; speedup vs baseline: 1.3568x; 1.1398x over previous
//
#include <hip/hip_runtime.h>

typedef _Float16 f16;
typedef _Float16 f16x8 __attribute__((ext_vector_type(8)));
typedef _Float16 f16x4 __attribute__((ext_vector_type(4)));
typedef float f32x4 __attribute__((ext_vector_type(4)));

#define MFMA_F16(A, B, C) __builtin_amdgcn_mfma_f32_16x16x32_f16(A, B, C, 0, 0, 0)

// ---------------- K1: 256x128 tile, BK=64, counted-vmcnt pipeline ----------------
// H = silu(X @ W1^T) * (X @ W3^T). M=16384, N(H)=2048, K=512|256.
// Same verified protocol as k2: 2-deep dbuf staged by global_load_lds w16,
// vmcnt(8) counted wait, raw s_barrier, both-sides row-XOR swizzle.
// 512 thr / 8 waves as 4M x 2N => per-wave 64x64 per GEMM (acc1+acc3 = 128 VGPR).
__global__ __launch_bounds__(512, 2) void k1_gate(
    const f16* __restrict__ A, int K,
    const f16* __restrict__ W1, const f16* __restrict__ W3,
    f16* __restrict__ Hout)
{
    __shared__ f16 As[2][256 * 64];   // 32 KB per buf
    __shared__ f16 B1s[2][128 * 64];  // 16 KB per buf
    __shared__ f16 B3s[2][128 * 64];  // 16 KB per buf   (total 128 KB)

    // XCD-chunked swizzle: nwg=1024 => 128 per XCD: each XCD runs 8 rb x 16 hb
    // (W1/W3 slices L2-resident, A-stripes shared within XCD).
    const int bid = blockIdx.x;
    const int swz = (bid & 7) * 128 + (bid >> 3);
    const int hb = swz & 15;   // H col-block (16 x 128)
    const int rb = swz >> 4;   // row-block (64 x 256)

    const int wid = threadIdx.x >> 6;
    const int lane = threadIdx.x & 63;
    const int wm = wid >> 1;  // 0..3 (M quarter: 64 rows)
    const int wn = wid & 1;   // 0..1 (N half: 64 cols)
    const int ln = lane & 15, lq = lane >> 4;

    const f16* Ab  = A  + (size_t)rb * 256 * 2048;  // obs_h ld = 2048
    const f16* B1b = W1 + (size_t)hb * 128 * K;
    const f16* B3b = W3 + (size_t)hb * 128 * K;
    const int NT = K >> 6;  // 8 (g0) or 4 (rest)

    // Stage K-tile kt into buf b: A 2048 chunks (4/thr), B1/B3 1024 chunks (2/thr each)
    // => 8 global_load_lds per thread per tile (same vmcnt accounting as k2).
    // LDS dest linear; global source pre-swizzled (p ^= row&7), rule #21.
#define K1_STAGE(kt, b)                                                                     \
    {                                                                                       \
        const f16* ga = Ab + (kt) * 64;                                                     \
        const f16* g1 = B1b + (kt) * 64;                                                    \
        const f16* g3 = B3b + (kt) * 64;                                                    \
        const int tt = threadIdx.x;                                                         \
        _Pragma("unroll")                                                                   \
        for (int i = 0; i < 4; ++i) {                                                       \
            int c = i * 512 + tt;                                                           \
            int row = c >> 3, p = c & 7, ps = p ^ (row & 7);                                \
            __builtin_amdgcn_global_load_lds(                                               \
                (const __attribute__((address_space(1))) void*)(ga + (size_t)row * 2048 + ps * 8), \
                (__attribute__((address_space(3))) void*)(&As[b][c * 8]), 16, 0, 0);        \
        }                                                                                   \
        _Pragma("unroll")                                                                   \
        for (int i = 0; i < 2; ++i) {                                                       \
            int c = i * 512 + tt;                                                           \
            int row = c >> 3, p = c & 7, ps = p ^ (row & 7);                                \
            __builtin_amdgcn_global_load_lds(                                               \
                (const __attribute__((address_space(1))) void*)(g1 + (size_t)row * K + ps * 8), \
                (__attribute__((address_space(3))) void*)(&B1s[b][c * 8]), 16, 0, 0);       \
        }                                                                                   \
        _Pragma("unroll")                                                                   \
        for (int i = 0; i < 2; ++i) {                                                       \
            int c = i * 512 + tt;                                                           \
            int row = c >> 3, p = c & 7, ps = p ^ (row & 7);                                \
            __builtin_amdgcn_global_load_lds(                                               \
                (const __attribute__((address_space(1))) void*)(g3 + (size_t)row * K + ps * 8), \
                (__attribute__((address_space(3))) void*)(&B3s[b][c * 8]), 16, 0, 0);       \
        }                                                                                   \
    }

    K1_STAGE(0, 0);
    K1_STAGE(1, 1);

    f32x4 acc1[4][4] = {};
    f32x4 acc3[4][4] = {};

    for (int t = 0; t < NT; ++t) {
        const int b = t & 1;
        // tile t landed (own wave's 8 oldest loads); tile t+1 may stay in flight (T4)
        if (t < NT - 1) {
            asm volatile("s_waitcnt vmcnt(8)" ::: "memory");
        } else {
            asm volatile("s_waitcnt vmcnt(0)" ::: "memory");
        }
        __builtin_amdgcn_sched_barrier(0);
        __builtin_amdgcn_s_barrier();   // all waves' chunks of tile t in LDS

        const char* Ap = (const char*)&As[b][0];
        const char* Bp1 = (const char*)&B1s[b][0];
        const char* Bp3 = (const char*)&B3s[b][0];

        f16x8 af[4][2], bf[4][2];
#pragma unroll
        for (int mi = 0; mi < 4; ++mi)
#pragma unroll
            for (int ks = 0; ks < 2; ++ks) {
                int row = wm * 64 + mi * 16 + ln;
                af[mi][ks] = *(const f16x8*)(Ap + row * 128 + ((ks * 64 + lq * 16) ^ ((row & 7) << 4)));
            }
#pragma unroll
        for (int ni = 0; ni < 4; ++ni)
#pragma unroll
            for (int ks = 0; ks < 2; ++ks) {
                int row = wn * 64 + ni * 16 + ln;
                bf[ni][ks] = *(const f16x8*)(Bp1 + row * 128 + ((ks * 64 + lq * 16) ^ ((row & 7) << 4)));
            }
        asm volatile("s_waitcnt lgkmcnt(0)" ::: "memory");
        __builtin_amdgcn_sched_barrier(0);

        __builtin_amdgcn_s_setprio(1);
#pragma unroll
        for (int mi = 0; mi < 4; ++mi)
#pragma unroll
            for (int ni = 0; ni < 4; ++ni) {
                acc1[mi][ni] = MFMA_F16(af[mi][0], bf[ni][0], acc1[mi][ni]);
                acc1[mi][ni] = MFMA_F16(af[mi][1], bf[ni][1], acc1[mi][ni]);
            }
        __builtin_amdgcn_s_setprio(0);

        // reload bf with W3 fragments (reuses regs)
#pragma unroll
        for (int ni = 0; ni < 4; ++ni)
#pragma unroll
            for (int ks = 0; ks < 2; ++ks) {
                int row = wn * 64 + ni * 16 + ln;
                bf[ni][ks] = *(const f16x8*)(Bp3 + row * 128 + ((ks * 64 + lq * 16) ^ ((row & 7) << 4)));
            }
        asm volatile("s_waitcnt lgkmcnt(0)" ::: "memory");  // ALL reads of buf b done
        __builtin_amdgcn_sched_barrier(0);
        __builtin_amdgcn_s_barrier();   // every wave done reading => overwrite safe

        if (t + 2 < NT) K1_STAGE(t + 2, b);

        __builtin_amdgcn_s_setprio(1);
#pragma unroll
        for (int mi = 0; mi < 4; ++mi)
#pragma unroll
            for (int ni = 0; ni < 4; ++ni) {
                acc3[mi][ni] = MFMA_F16(af[mi][0], bf[ni][0], acc3[mi][ni]);
                acc3[mi][ni] = MFMA_F16(af[mi][1], bf[ni][1], acc3[mi][ni]);
            }
        __builtin_amdgcn_s_setprio(0);
    }

    // ---- epilogue: silu(g1)*g3, direct f16 stores (32B segments; measured neutral vs bounce) ----
    const size_t row0 = (size_t)rb * 256 + wm * 64;
    const int col0 = hb * 128 + wn * 64;
#pragma unroll
    for (int mi = 0; mi < 4; ++mi)
#pragma unroll
        for (int r = 0; r < 4; ++r) {
            size_t row = row0 + mi * 16 + lq * 4 + r;
#pragma unroll
            for (int ni = 0; ni < 4; ++ni) {
                float g1 = acc1[mi][ni][r];
                float g3 = acc3[mi][ni][r];
                float h = g1 / (1.f + __expf(-g1)) * g3;  // silu(g1)*g3
                Hout[row * 2048 + col0 + ni * 16 + ln] = (f16)h;
            }
        }
}

// ---------------- K2: 256^2 tile, BK=64, counted-vmcnt pipeline (unchanged, round-3 verified) ----------------
#define K2NT 32
__global__ __launch_bounds__(512, 2) void k2_out(
    const f16* __restrict__ Hm, const f16* __restrict__ W2,
    float* __restrict__ outp,   // d_out + g*1024, row stride 7168
    float* __restrict__ ssp)    // ss + g*4*16384, layout [cb][b]
{
    __shared__ f16 As[2][256 * 64];
    __shared__ f16 Bs[2][256 * 64];
    __shared__ float ssTile[256];

    const int bid = blockIdx.x;
    const int swz = (bid & 7) * 32 + (bid >> 3);
    const int cb = swz & 3;   // out col-block (4)
    const int rb = swz >> 2;  // row-block (64)

    const int wid = threadIdx.x >> 6;
    const int lane = threadIdx.x & 63;
    const int wm = wid >> 2;  // 0..1 (M half)
    const int wn = wid & 3;   // 0..3 (N quarter)
    const int ln = lane & 15, lq = lane >> 4;

    if (threadIdx.x < 256) ssTile[threadIdx.x] = 0.f;

    const f16* Ab = Hm + (size_t)rb * 256 * 2048;
    const f16* Bb = W2 + (size_t)cb * 256 * 2048;

#define K2_STAGE(kt, b)                                                                     \
    {                                                                                       \
        const f16* ga = Ab + (kt) * 64;                                                     \
        const f16* gb = Bb + (kt) * 64;                                                     \
        const int tt = threadIdx.x;                                                         \
        _Pragma("unroll")                                                                   \
        for (int i = 0; i < 4; ++i) {                                                       \
            int c = i * 512 + tt;                                                           \
            int row = c >> 3, p = c & 7, ps = p ^ (row & 7);                                \
            __builtin_amdgcn_global_load_lds(                                               \
                (const __attribute__((address_space(1))) void*)(ga + (size_t)row * 2048 + ps * 8), \
                (__attribute__((address_space(3))) void*)(&As[b][c * 8]), 16, 0, 0);        \
        }                                                                                   \
        _Pragma("unroll")                                                                   \
        for (int i = 0; i < 4; ++i) {                                                       \
            int c = i * 512 + tt;                                                           \
            int row = c >> 3, p = c & 7, ps = p ^ (row & 7);                                \
            __builtin_amdgcn_global_load_lds(                                               \
                (const __attribute__((address_space(1))) void*)(gb + (size_t)row * 2048 + ps * 8), \
                (__attribute__((address_space(3))) void*)(&Bs[b][c * 8]), 16, 0, 0);        \
        }                                                                                   \
    }

    K2_STAGE(0, 0);
    K2_STAGE(1, 1);

    f32x4 acc[8][4] = {};

    for (int t = 0; t < K2NT; ++t) {
        const int b = t & 1;
        asm volatile("s_waitcnt vmcnt(8)" ::: "memory");
        __builtin_amdgcn_sched_barrier(0);
        __builtin_amdgcn_s_barrier();

        const char* Ap = (const char*)&As[b][0];
        const char* Bp = (const char*)&Bs[b][0];

        f16x8 bf[4][2], af[4][2];
#pragma unroll
        for (int ni = 0; ni < 4; ++ni)
#pragma unroll
            for (int ks = 0; ks < 2; ++ks) {
                int row = wn * 64 + ni * 16 + ln;
                bf[ni][ks] = *(const f16x8*)(Bp + row * 128 + ((ks * 64 + lq * 16) ^ ((row & 7) << 4)));
            }
#pragma unroll
        for (int mi = 0; mi < 4; ++mi)
#pragma unroll
            for (int ks = 0; ks < 2; ++ks) {
                int row = wm * 128 + mi * 16 + ln;
                af[mi][ks] = *(const f16x8*)(Ap + row * 128 + ((ks * 64 + lq * 16) ^ ((row & 7) << 4)));
            }
        asm volatile("s_waitcnt lgkmcnt(0)" ::: "memory");
        __builtin_amdgcn_sched_barrier(0);

        __builtin_amdgcn_s_setprio(1);
#pragma unroll
        for (int mi = 0; mi < 4; ++mi)
#pragma unroll
            for (int ni = 0; ni < 4; ++ni) {
                acc[mi][ni] = MFMA_F16(af[mi][0], bf[ni][0], acc[mi][ni]);
                acc[mi][ni] = MFMA_F16(af[mi][1], bf[ni][1], acc[mi][ni]);
            }
        __builtin_amdgcn_s_setprio(0);

#pragma unroll
        for (int mi = 0; mi < 4; ++mi)
#pragma unroll
            for (int ks = 0; ks < 2; ++ks) {
                int row = wm * 128 + 64 + mi * 16 + ln;
                af[mi][ks] = *(const f16x8*)(Ap + row * 128 + ((ks * 64 + lq * 16) ^ ((row & 7) << 4)));
            }
        asm volatile("s_waitcnt lgkmcnt(0)" ::: "memory");
        __builtin_amdgcn_sched_barrier(0);
        __builtin_amdgcn_s_barrier();

        K2_STAGE((t + 2) & (K2NT - 1), b);

        __builtin_amdgcn_s_setprio(1);
#pragma unroll
        for (int mi = 0; mi < 4; ++mi)
#pragma unroll
            for (int ni = 0; ni < 4; ++ni) {
                acc[4 + mi][ni] = MFMA_F16(af[mi][0], bf[ni][0], acc[4 + mi][ni]);
                acc[4 + mi][ni] = MFMA_F16(af[mi][1], bf[ni][1], acc[4 + mi][ni]);
            }
        __builtin_amdgcn_s_setprio(0);
    }

    const size_t grow0 = (size_t)rb * 256 + wm * 128;
    const int gcol0 = cb * 256 + wn * 64;
#pragma unroll
    for (int mi8 = 0; mi8 < 8; ++mi8)
#pragma unroll
        for (int r = 0; r < 4; ++r) {
            int lrl = (mi8 >> 2) * 64 + (mi8 & 3) * 16 + lq * 4 + r;
            int lrow = wm * 128 + lrl;
            size_t grow = grow0 + lrl;
            float s = 0.f;
#pragma unroll
            for (int ni = 0; ni < 4; ++ni) {
                float c = acc[mi8][ni][r];
                s += c * c;
                outp[grow * 7168 + gcol0 + ni * 16 + ln] = c;
            }
            s += __shfl_xor(s, 1);
            s += __shfl_xor(s, 2);
            s += __shfl_xor(s, 4);
            s += __shfl_xor(s, 8);
            if (ln == 0) atomicAdd(&ssTile[lrow], s);
        }
    __syncthreads();
    if (threadIdx.x < 256)
        ssp[(size_t)cb * 16384 + rb * 256 + threadIdx.x] = ssTile[threadIdx.x];
}

// ---------------- K3: in-place RMS norm + affine + term_embed ----------------
__global__ __launch_bounds__(256) void k3_norm(
    float* __restrict__ outp, const float* __restrict__ ss,
    const float* __restrict__ nw, const float* __restrict__ nb,
    const float* __restrict__ te)
{
    const int rrow = blockIdx.x;  // b*7 + g
    const int g = rrow % 7;
    const int b = rrow / 7;
    float ssum = 0.f;
#pragma unroll
    for (int cb = 0; cb < 4; ++cb) ssum += ss[(size_t)(g * 4 + cb) * 16384 + b];
    const float rinv = 1.0f / sqrtf(ssum * (1.0f / 1024.0f) + 1e-5f);
    const int t = threadIdx.x;
    float4* rowp = (float4*)(outp + (size_t)rrow * 1024);
    float4 x = rowp[t];
    float4 w = ((const float4*)nw)[t];
    float4 bb = ((const float4*)nb)[t];
    float4 e = ((const float4*)(te + g * 1024))[t];
    float4 o;
    o.x = x.x * rinv * w.x + bb.x + e.x;
    o.y = x.y * rinv * w.y + bb.y + e.y;
    o.z = x.z * rinv * w.z + bb.z + e.z;
    o.w = x.w * rinv * w.w + bb.w + e.w;
    rowp[t] = o;
}

// ---------------- K0: fp32 -> f16 convert (n multiple of 1024) ----------------
__global__ __launch_bounds__(256) void cvt_f16(const float* __restrict__ s, f16* __restrict__ d) {
    size_t i = (size_t)blockIdx.x * 256 + threadIdx.x;
    float4 v = ((const float4*)s)[i];
    f16x4 o = { (f16)v.x, (f16)v.y, (f16)v.z, (f16)v.w };
    ((f16x4*)d)[i] = o;
}

extern "C" void kernel_launch(void* const* d_in, const int* in_sizes, int n_in,
                              void* d_out, int out_size, void* d_ws, size_t ws_size,
                              hipStream_t stream) {
    const float* obs  = (const float*)d_in[0];
    const float* w1g0 = (const float*)d_in[1];
    const float* w3g0 = (const float*)d_in[2];
    const float* w2g0 = (const float*)d_in[3];
    const float* w1r  = (const float*)d_in[4];
    const float* w3r  = (const float*)d_in[5];
    const float* w2r  = (const float*)d_in[6];
    const float* nw   = (const float*)d_in[7];
    const float* nb   = (const float*)d_in[8];
    const float* te   = (const float*)d_in[9];

    f16* obs_h  = (f16*)d_ws;
    f16* w1g0_h = obs_h  + 33554432;
    f16* w3g0_h = w1g0_h + 1048576;
    f16* w2g0_h = w3g0_h + 1048576;
    f16* w1r_h  = w2g0_h + 2097152;
    f16* w3r_h  = w1r_h  + 3145728;
    f16* w2r_h  = w3r_h  + 3145728;
    f16* Hbuf   = w2r_h  + 12582912;
    float* ssb  = (float*)(Hbuf + 33554432);

    cvt_f16<<<33554432 / 1024, 256, 0, stream>>>(obs, obs_h);
    cvt_f16<<<1048576 / 1024, 256, 0, stream>>>(w1g0, w1g0_h);
    cvt_f16<<<1048576 / 1024, 256, 0, stream>>>(w3g0, w3g0_h);
    cvt_f16<<<2097152 / 1024, 256, 0, stream>>>(w2g0, w2g0_h);
    cvt_f16<<<3145728 / 1024, 256, 0, stream>>>(w1r, w1r_h);
    cvt_f16<<<3145728 / 1024, 256, 0, stream>>>(w3r, w3r_h);
    cvt_f16<<<12582912 / 1024, 256, 0, stream>>>(w2r, w2r_h);

    for (int g = 0; g < 7; ++g) {
        const f16* A  = obs_h + (g == 0 ? 0 : 512 + (g - 1) * 256);
        int K         = (g == 0) ? 512 : 256;
        const f16* W1 = (g == 0) ? w1g0_h : w1r_h + (size_t)(g - 1) * 2048 * 256;
        const f16* W3 = (g == 0) ? w3g0_h : w3r_h + (size_t)(g - 1) * 2048 * 256;
        const f16* W2 = (g == 0) ? w2g0_h : w2r_h + (size_t)(g - 1) * 1024 * 2048;
        k1_gate<<<1024, 512, 0, stream>>>(A, K, W1, W3, Hbuf);
        k2_out<<<256, 512, 0, stream>>>(Hbuf, W2, (float*)d_out + g * 1024,
                                        ssb + (size_t)g * 4 * 16384);
    }
    k3_norm<<<114688, 256, 0, stream>>>((float*)d_out, ssb, nw, nb, te);
}